// Round 2
// baseline (792.853 us; speedup 1.0000x reference)
//
#include <hip/hip_runtime.h>
#include <stdint.h>

#define NB 8
#define NH 96
#define NW_ 96
#define NA 9
#define NANCH (NH * NW_ * NA)   // 82944
#define KPRE 4000
#define MAXOUT 2000
#define KEYCAP 4224             // >= KPRE + max expected cut-bucket size
#define WPR 64                  // mask row stride in u64 words (63 used + 1 pad)
#define NWORDS 63               // ceil(4000/64)

// ---------------- Kernel 1: per-batch histogram of score bits ----------------
__global__ void k_hist(const float* __restrict__ score, unsigned* __restrict__ hist) {
    const int b = blockIdx.y;
    __shared__ unsigned h[4096];
    for (int i = threadIdx.x; i < 4096; i += blockDim.x) h[i] = 0u;
    __syncthreads();
    const float* s = score + (size_t)b * NANCH;
    int start = blockIdx.x * blockDim.x + threadIdx.x;
    int stride = gridDim.x * blockDim.x;
    for (int i = start; i < NANCH; i += stride) {
        float v = s[i];
        if (v > 0.5f) {
            unsigned bits = __float_as_uint(v);
            atomicAdd(&h[(bits >> 11) & 4095u], 1u);
        }
    }
    __syncthreads();
    for (int k = threadIdx.x; k < 4096; k += blockDim.x) {
        unsigned c = h[k];
        if (c) atomicAdd(&hist[b * 4096 + k], c);
    }
}

// ------- Kernel 2: suffix-sum -> bucket starts, cut, P, M; zero hist->bcnt ----
__global__ void k_cut(unsigned* __restrict__ hist, unsigned* __restrict__ start,
                      unsigned* __restrict__ meta) {
    const int b = blockIdx.x;
    __shared__ unsigned sa[4096];
    __shared__ unsigned sb[4096];
    unsigned* src = sa;
    unsigned* dst = sb;
    for (int k = threadIdx.x; k < 4096; k += blockDim.x) {
        sa[k] = hist[b * 4096 + k];
        hist[b * 4096 + k] = 0u;     // region becomes bcnt for k_collect
    }
    __syncthreads();
    for (int d = 1; d < 4096; d <<= 1) {
        for (int k = threadIdx.x; k < 4096; k += blockDim.x)
            dst[k] = src[k] + ((k + d < 4096) ? src[k + d] : 0u);
        __syncthreads();
        unsigned* t = src; src = dst; dst = t;
    }
    // src[k] = sfx[k] = count of candidates in buckets >= k
    for (int k = threadIdx.x; k < 4096; k += blockDim.x)
        start[b * 4096 + k] = (k + 1 < 4096) ? src[k + 1] : 0u;
    if (threadIdx.x == 0) {
        unsigned total = src[0];
        unsigned P = total < KEYCAP ? total : KEYCAP;
        meta[b] = 0u;
        meta[8 + b] = P;
        meta[16 + b] = P < KPRE ? P : KPRE;
    }
    __syncthreads();
    for (int k = threadIdx.x; k < 4096; k += blockDim.x) {
        unsigned sfx = src[k];
        unsigned nxt = (k + 1 < 4096) ? src[k + 1] : 0u;
        if (sfx >= (unsigned)KPRE && nxt < (unsigned)KPRE) {
            unsigned P = sfx < KEYCAP ? sfx : KEYCAP;
            meta[b] = (unsigned)k;
            meta[8 + b] = P;
            meta[16 + b] = (unsigned)KPRE;
        }
    }
}

// ---------------- Kernel 3: bucketed scatter of candidate keys ---------------
__global__ void k_collect(const float* __restrict__ score, const unsigned* __restrict__ meta,
                          const unsigned* __restrict__ start, unsigned* __restrict__ bcnt,
                          unsigned long long* __restrict__ keys) {
    const int b = blockIdx.y;
    const unsigned cut = meta[b];
    const float* sc = score + (size_t)b * NANCH;
    int i0 = blockIdx.x * blockDim.x + threadIdx.x;
    int stride = gridDim.x * blockDim.x;
    for (int i = i0; i < NANCH; i += stride) {
        float v = sc[i];
        if (v > 0.5f) {
            unsigned bits = __float_as_uint(v);
            unsigned bucket = (bits >> 11) & 4095u;
            if (bucket >= cut) {
                unsigned pos = start[b * 4096 + bucket] + atomicAdd(&bcnt[b * 4096 + bucket], 1u);
                if (pos < (unsigned)KEYCAP)
                    keys[(size_t)b * KEYCAP + pos] =
                        ((unsigned long long)bits << 32) | (unsigned)(~(unsigned)i);
            }
        }
    }
}

// -------- Kernel 4: rank within bucket (exact sort position) + decode --------
__global__ void k_rank_decode(const unsigned long long* __restrict__ keys,
                              const unsigned* __restrict__ start,
                              const unsigned* __restrict__ meta,
                              const float* __restrict__ delta,
                              const float* __restrict__ anchors,
                              float* __restrict__ cand) {
#pragma clang fp contract(off)
    const int b = blockIdx.y;
    const int s = blockIdx.x * blockDim.x + threadIdx.x;
    const int P = (int)meta[8 + b];
    const int M = (int)meta[16 + b];
    // zero cand rows [M, KPRE) so downstream kernels see deterministic data
    if (s >= M && s < KPRE) {
        float4* c4 = (float4*)(cand + (size_t)b * KPRE * 4);
        c4[s] = make_float4(0.f, 0.f, 0.f, 0.f);
    }
    if (s >= P) return;
    const unsigned long long* kb = keys + (size_t)b * KEYCAP;
    unsigned long long key = kb[s];
    unsigned bucket = (unsigned)(key >> 43) & 4095u;
    int base = (int)start[b * 4096 + bucket];
    int end = (bucket > 0) ? (int)start[b * 4096 + bucket - 1] : P;
    if (end > P) end = P;
    int rank = 0;
    for (int t = base; t < end; ++t) rank += (kb[t] > key) ? 1 : 0;
    int pos = base + rank;
    if (pos >= KPRE) return;
    int n = (int)(~(unsigned)(key & 0xFFFFFFFFull));
    float4 t4 = *(const float4*)(delta + ((size_t)b * NANCH + n) * 4);
    float4 a4 = *(const float4*)(anchors + (size_t)n * 4);
    float xa = (a4.x + a4.y) * 0.5f;
    float ya = (a4.z + a4.w) * 0.5f;
    float wa = a4.y - a4.x;
    float ha = a4.w - a4.z;
    float x = t4.x * wa + xa;
    float y = t4.y * ha + ya;
    float w = expf(t4.z) * wa;
    float h = expf(t4.w) * ha;
    float xmn = fminf(fmaxf(x - w * 0.5f, 0.f), 1.f);
    float xmx = fminf(fmaxf(x + w * 0.5f, 0.f), 1.f);
    float ymn = fminf(fmaxf(y - h * 0.5f, 0.f), 1.f);
    float ymx = fminf(fmaxf(y + h * 0.5f, 0.f), 1.f);
    float* o = cand + ((size_t)b * KPRE + pos) * 4;
    o[0] = xmn; o[1] = xmx; o[2] = ymn; o[3] = ymx;
}

// ---------------- Kernel 5: upper-triangle suppression bit matrix ------------
__global__ void k_mask(const float* __restrict__ cand, unsigned long long* __restrict__ mask) {
#pragma clang fp contract(off)
    const int b = blockIdx.y;
    const int c = blockIdx.x;   // row chunk of 64
    __shared__ float4 sb4[KPRE];  // 64000 B
    {
        const float4* c4 = (const float4*)(cand + (size_t)b * KPRE * 4);
        for (int k = threadIdx.x; k < KPRE; k += blockDim.x) sb4[k] = c4[k];
    }
    __syncthreads();
    for (int task = threadIdx.x; task < 64 * NWORDS; task += blockDim.x) {
        const int ri = task & 63;   // lane -> row (consecutive), word uniform per wave
        const int w = task >> 6;
        const int i = (c << 6) + ri;
        if (i >= KPRE) continue;
        unsigned long long bits = 0ull;
        if (w >= c) {               // row's own word index == c (uniform per block)
            float4 bi = sb4[i];
            float ai = (bi.y - bi.x) * (bi.w - bi.z);
            const int j0 = w << 6;
            const int jlim = (j0 + 64 <= KPRE) ? 64 : (KPRE - j0);
            int jj = (w == c) ? ri + 1 : 0;
            for (; jj < jlim; ++jj) {
                float4 bj = sb4[j0 + jj];
                float iw = fminf(bi.y, bj.y) - fmaxf(bi.x, bj.x);
                iw = fmaxf(iw, 0.0f);
                float ih = fminf(bi.w, bj.w) - fmaxf(bi.z, bj.z);
                ih = fmaxf(ih, 0.0f);
                float inter = iw * ih;
                float aj = (bj.y - bj.x) * (bj.w - bj.z);
                float uni = ai + aj - inter;
                float iou = inter / fmaxf(uni, 1e-8f);
                if (iou > 0.7f) bits |= (1ull << jj);
            }
        }
        mask[((size_t)b * KPRE + i) * WPR + w] = bits;
    }
}

// -------- Kernel 6: greedy NMS, chunk-scalar scan (one wave per batch) -------
__global__ __launch_bounds__(64) void k_nms(const unsigned long long* __restrict__ mask,
                                            const float* __restrict__ cand,
                                            const unsigned* __restrict__ meta,
                                            float* __restrict__ out) {
    const int b = blockIdx.x;
    const int lane = threadIdx.x;
    const int M = (int)meta[16 + b];
    const unsigned long long* mrow = mask + (size_t)b * KPRE * WPR;
    __shared__ int sel[MAXOUT];
    unsigned long long rem = 0ull;   // lane l holds suppression word l (rows 64l..64l+63)
    int cnt = 0;
    const int nchunks = (M + 63) >> 6;

    // diag for chunk 0: lane l = word 0 of row l (intra-chunk suppression bits)
    unsigned long long diag = (nchunks > 0 && lane < M) ? mrow[(size_t)lane * WPR + 0] : 0ull;

    for (int c = 0; c < nchunks && cnt < MAXOUT; ++c) {
        const int j0 = c << 6;
        // prefetch next chunk's diag (latency hides under this chunk's scan)
        unsigned long long diag_nx = 0ull;
        {
            int rn = j0 + 64 + lane;
            if (c + 1 < nchunks && rn < M) diag_nx = mrow[(size_t)rn * WPR + (c + 1)];
        }
        unsigned long long cur = __shfl(rem, c);   // uniform: chunk's suppressed bits
        int nrow = M - j0;
        unsigned long long live = ~cur;
        if (nrow < 64) live &= (1ull << nrow) - 1ull;

        unsigned long long q0 = 0, q1 = 0, q2 = 0, q3 = 0;  // pending mask-row loads
        while (live && cnt < MAXOUT) {
            int jj = __builtin_ctzll(live);
            if (lane == 0) sel[cnt] = j0 + jj;
            ++cnt;
            unsigned long long dw = __shfl(diag, jj);       // row jj's intra-chunk bits
            rem |= q3; q3 = q2; q2 = q1; q1 = q0;           // retire oldest pending load
            q0 = mrow[(size_t)(j0 + jj) * WPR + lane];      // issue this accept's row
            live &= ~(dw | (1ull << jj));
        }
        rem |= (q0 | q1) | (q2 | q3);   // flush before next chunk consumes rem
        diag = diag_nx;
    }

    __syncthreads();
    const float4* c4 = (const float4*)(cand + (size_t)b * KPRE * 4);
    float4* o4 = (float4*)(out + (size_t)b * MAXOUT * 4);
    for (int r = lane; r < MAXOUT; r += 64) {
        float4 v = make_float4(0.0f, 0.0f, 0.0f, 0.0f);
        if (r < cnt) v = c4[sel[r]];
        o4[r] = v;
    }
}

// ---------------- launch ------------------------------------------------------
extern "C" void kernel_launch(void* const* d_in, const int* in_sizes, int n_in,
                              void* d_out, int out_size, void* d_ws, size_t ws_size,
                              hipStream_t stream) {
    const float* score   = (const float*)d_in[0];
    const float* delta   = (const float*)d_in[1];
    const float* anchors = (const float*)d_in[2];
    float* out = (float*)d_out;

    uint8_t* w8 = (uint8_t*)d_ws;
    // layout (bytes):
    //   hist/bcnt : [0, 131072)            8 x 4096 u32 (hist, then reused as bcnt)
    //   start     : [131072, 262144)       8 x 4096 u32 bucket start offsets
    //   meta      : [262144, 262272)       cut[8] | P[8] | M[8]
    //   keys      : [262272, 532608)       8 x 4224 u64
    //   cand      : [532608, 1044608)      8 x 4000 x 4 f32
    //   mask      : [1044608, 17428608)    8 x 4000 x 64 u64
    unsigned* hist = (unsigned*)(w8 + 0);
    unsigned* start = (unsigned*)(w8 + 131072);
    unsigned* meta = (unsigned*)(w8 + 262144);
    unsigned long long* keys = (unsigned long long*)(w8 + 262272);
    float* cand = (float*)(w8 + 532608);
    unsigned long long* mask = (unsigned long long*)(w8 + 1044608);

    hipMemsetAsync(hist, 0, 8 * 4096 * sizeof(unsigned), stream);
    k_hist<<<dim3(16, NB), 256, 0, stream>>>(score, hist);
    k_cut<<<NB, 1024, 0, stream>>>(hist, start, meta);
    k_collect<<<dim3(32, NB), 256, 0, stream>>>(score, meta, start, hist /*bcnt*/, keys);
    k_rank_decode<<<dim3((KEYCAP + 255) / 256, NB), 256, 0, stream>>>(keys, start, meta,
                                                                      delta, anchors, cand);
    k_mask<<<dim3((KPRE + 63) / 64, NB), 256, 0, stream>>>(cand, mask);
    k_nms<<<NB, 64, 0, stream>>>(mask, cand, meta, out);
}

// Round 3
// 402.332 us; speedup vs baseline: 1.9706x; 1.9706x over previous
//
#include <hip/hip_runtime.h>
#include <stdint.h>

#define NB 8
#define NH 96
#define NW_ 96
#define NA 9
#define NANCH (NH * NW_ * NA)   // 82944
#define KPRE 4000
#define MAXOUT 2000
#define KEYCAP 4224             // >= KPRE + max expected cut-bucket size
#define WPR 64                  // mask row stride in u64 words (63 used + 1 pad)
#define NWORDS 63               // ceil(4000/64)

// ---------------- Kernel 1: per-batch histogram of score bits ----------------
__global__ void k_hist(const float* __restrict__ score, unsigned* __restrict__ hist) {
    const int b = blockIdx.y;
    __shared__ unsigned h[4096];
    for (int i = threadIdx.x; i < 4096; i += blockDim.x) h[i] = 0u;
    __syncthreads();
    const float* s = score + (size_t)b * NANCH;
    int start = blockIdx.x * blockDim.x + threadIdx.x;
    int stride = gridDim.x * blockDim.x;
    for (int i = start; i < NANCH; i += stride) {
        float v = s[i];
        if (v > 0.5f) {
            unsigned bits = __float_as_uint(v);
            atomicAdd(&h[(bits >> 11) & 4095u], 1u);
        }
    }
    __syncthreads();
    for (int k = threadIdx.x; k < 4096; k += blockDim.x) {
        unsigned c = h[k];
        if (c) atomicAdd(&hist[b * 4096 + k], c);
    }
}

// ------- Kernel 2: suffix-sum -> bucket starts, cut, P, M; zero hist->bcnt ----
__global__ void k_cut(unsigned* __restrict__ hist, unsigned* __restrict__ start,
                      unsigned* __restrict__ meta) {
    const int b = blockIdx.x;
    __shared__ unsigned sa[4096];
    __shared__ unsigned sb[4096];
    unsigned* src = sa;
    unsigned* dst = sb;
    for (int k = threadIdx.x; k < 4096; k += blockDim.x) {
        sa[k] = hist[b * 4096 + k];
        hist[b * 4096 + k] = 0u;     // region becomes bcnt for k_collect
    }
    __syncthreads();
    for (int d = 1; d < 4096; d <<= 1) {
        for (int k = threadIdx.x; k < 4096; k += blockDim.x)
            dst[k] = src[k] + ((k + d < 4096) ? src[k + d] : 0u);
        __syncthreads();
        unsigned* t = src; src = dst; dst = t;
    }
    // src[k] = sfx[k] = count of candidates in buckets >= k
    for (int k = threadIdx.x; k < 4096; k += blockDim.x)
        start[b * 4096 + k] = (k + 1 < 4096) ? src[k + 1] : 0u;
    if (threadIdx.x == 0) {
        unsigned total = src[0];
        unsigned P = total < KEYCAP ? total : KEYCAP;
        meta[b] = 0u;
        meta[8 + b] = P;
        meta[16 + b] = P < KPRE ? P : KPRE;
    }
    __syncthreads();
    for (int k = threadIdx.x; k < 4096; k += blockDim.x) {
        unsigned sfx = src[k];
        unsigned nxt = (k + 1 < 4096) ? src[k + 1] : 0u;
        if (sfx >= (unsigned)KPRE && nxt < (unsigned)KPRE) {
            unsigned P = sfx < KEYCAP ? sfx : KEYCAP;
            meta[b] = (unsigned)k;
            meta[8 + b] = P;
            meta[16 + b] = (unsigned)KPRE;
        }
    }
}

// ---------------- Kernel 3: bucketed scatter of candidate keys ---------------
__global__ void k_collect(const float* __restrict__ score, const unsigned* __restrict__ meta,
                          const unsigned* __restrict__ start, unsigned* __restrict__ bcnt,
                          unsigned long long* __restrict__ keys) {
    const int b = blockIdx.y;
    const unsigned cut = meta[b];
    const float* sc = score + (size_t)b * NANCH;
    int i0 = blockIdx.x * blockDim.x + threadIdx.x;
    int stride = gridDim.x * blockDim.x;
    for (int i = i0; i < NANCH; i += stride) {
        float v = sc[i];
        if (v > 0.5f) {
            unsigned bits = __float_as_uint(v);
            unsigned bucket = (bits >> 11) & 4095u;
            if (bucket >= cut) {
                unsigned pos = start[b * 4096 + bucket] + atomicAdd(&bcnt[b * 4096 + bucket], 1u);
                if (pos < (unsigned)KEYCAP)
                    keys[(size_t)b * KEYCAP + pos] =
                        ((unsigned long long)bits << 32) | (unsigned)(~(unsigned)i);
            }
        }
    }
}

// -------- Kernel 4: rank within bucket (exact sort position) + decode --------
__global__ void k_rank_decode(const unsigned long long* __restrict__ keys,
                              const unsigned* __restrict__ start,
                              const unsigned* __restrict__ meta,
                              const float* __restrict__ delta,
                              const float* __restrict__ anchors,
                              float* __restrict__ cand) {
#pragma clang fp contract(off)
    const int b = blockIdx.y;
    const int s = blockIdx.x * blockDim.x + threadIdx.x;
    const int P = (int)meta[8 + b];
    const int M = (int)meta[16 + b];
    // zero cand rows [M, KPRE) so downstream kernels see deterministic data
    if (s >= M && s < KPRE) {
        float4* c4 = (float4*)(cand + (size_t)b * KPRE * 4);
        c4[s] = make_float4(0.f, 0.f, 0.f, 0.f);
    }
    if (s >= P) return;
    const unsigned long long* kb = keys + (size_t)b * KEYCAP;
    unsigned long long key = kb[s];
    unsigned bucket = (unsigned)(key >> 43) & 4095u;
    int base = (int)start[b * 4096 + bucket];
    int end = (bucket > 0) ? (int)start[b * 4096 + bucket - 1] : P;
    if (end > P) end = P;
    int rank = 0;
    for (int t = base; t < end; ++t) rank += (kb[t] > key) ? 1 : 0;
    int pos = base + rank;
    if (pos >= KPRE) return;
    int n = (int)(~(unsigned)(key & 0xFFFFFFFFull));
    float4 t4 = *(const float4*)(delta + ((size_t)b * NANCH + n) * 4);
    float4 a4 = *(const float4*)(anchors + (size_t)n * 4);
    float xa = (a4.x + a4.y) * 0.5f;
    float ya = (a4.z + a4.w) * 0.5f;
    float wa = a4.y - a4.x;
    float ha = a4.w - a4.z;
    float x = t4.x * wa + xa;
    float y = t4.y * ha + ya;
    float w = expf(t4.z) * wa;
    float h = expf(t4.w) * ha;
    float xmn = fminf(fmaxf(x - w * 0.5f, 0.f), 1.f);
    float xmx = fminf(fmaxf(x + w * 0.5f, 0.f), 1.f);
    float ymn = fminf(fmaxf(y - h * 0.5f, 0.f), 1.f);
    float ymx = fminf(fmaxf(y + h * 0.5f, 0.f), 1.f);
    float* o = cand + ((size_t)b * KPRE + pos) * 4;
    o[0] = xmn; o[1] = xmx; o[2] = ymn; o[3] = ymx;
}

// ---------------- Kernel 5: upper-triangle suppression bit matrix ------------
__global__ void k_mask(const float* __restrict__ cand, unsigned long long* __restrict__ mask) {
#pragma clang fp contract(off)
    const int b = blockIdx.y;
    const int c = blockIdx.x;   // row chunk of 64
    __shared__ float4 sb4[KPRE];  // 64000 B
    {
        const float4* c4 = (const float4*)(cand + (size_t)b * KPRE * 4);
        for (int k = threadIdx.x; k < KPRE; k += blockDim.x) sb4[k] = c4[k];
    }
    __syncthreads();
    for (int task = threadIdx.x; task < 64 * NWORDS; task += blockDim.x) {
        const int ri = task & 63;   // lane -> row (consecutive), word uniform per wave
        const int w = task >> 6;
        const int i = (c << 6) + ri;
        if (i >= KPRE) continue;
        unsigned long long bits = 0ull;
        if (w >= c) {               // row's own word index == c (uniform per block)
            float4 bi = sb4[i];
            float ai = (bi.y - bi.x) * (bi.w - bi.z);
            const int j0 = w << 6;
            const int jlim = (j0 + 64 <= KPRE) ? 64 : (KPRE - j0);
            int jj = (w == c) ? ri + 1 : 0;
            for (; jj < jlim; ++jj) {
                float4 bj = sb4[j0 + jj];
                float iw = fminf(bi.y, bj.y) - fmaxf(bi.x, bj.x);
                iw = fmaxf(iw, 0.0f);
                float ih = fminf(bi.w, bj.w) - fmaxf(bi.z, bj.z);
                ih = fmaxf(ih, 0.0f);
                float inter = iw * ih;
                float aj = (bj.y - bj.x) * (bj.w - bj.z);
                float uni = ai + aj - inter;
                float iou = inter / fmaxf(uni, 1e-8f);
                if (iou > 0.7f) bits |= (1ull << jj);
            }
        }
        mask[((size_t)b * KPRE + i) * WPR + w] = bits;
    }
}

// ---- Kernel 6: greedy NMS, ctz scan + LDS-prefetched chunk masks ------------
__device__ __forceinline__ void gl_lds16(const void* g, void* l) {
    __builtin_amdgcn_global_load_lds(
        (const __attribute__((address_space(1))) void*)g,
        (__attribute__((address_space(3))) void*)l, 16, 0, 0);
}

__global__ __launch_bounds__(64) void k_nms(const unsigned long long* __restrict__ mask,
                                            const float* __restrict__ cand,
                                            const unsigned* __restrict__ meta,
                                            float* __restrict__ out) {
    const int b = blockIdx.x;
    const int lane = threadIdx.x;
    const int M = (int)meta[16 + b];
    const unsigned long long* mrow = mask + (size_t)b * KPRE * WPR;
    __shared__ int sel[MAXOUT];                      // 8 KB
    __shared__ unsigned long long buf[2 * 64 * 64];  // 2 x 32 KB double buffer
    unsigned long long rem = 0ull;   // lane l holds suppression word l (rows 64l..)
    int cnt = 0;
    const int nchunks = (M + 63) >> 6;

    // prefetch chunk cc's 64 mask rows (64 x 512B) into buf[(cc&1)]
    auto prefetch = [&](int cc) {
        if (cc >= nchunks) return;
        const int j0 = cc << 6;
        const int nrows = (KPRE - j0) < 64 ? (KPRE - j0) : 64;   // always even
        const int ninstr = nrows >> 1;                           // 1KB per instr
        const char* gsrc = (const char*)(mrow + (size_t)j0 * WPR) + lane * 16;
        char* ldst = (char*)buf + (size_t)(cc & 1) * 32768;
        for (int k = 0; k < ninstr; ++k)
            gl_lds16(gsrc + k * 1024, ldst + k * 1024);
    };

    prefetch(0);
    for (int c = 0; c < nchunks && cnt < MAXOUT; ++c) {
        // drain DS pipe (prev chunk's fold reads) before overwriting that buffer,
        // then ensure this chunk's buffer has landed.
        asm volatile("s_waitcnt lgkmcnt(0)" ::: "memory");
        asm volatile("s_waitcnt vmcnt(0)" ::: "memory");
        prefetch(c + 1);

        const unsigned long long* bufc = buf + (size_t)(c & 1) * 4096;
        const int j0 = c << 6;
        // diag: lane l = word c of row j0+l (intra-chunk suppression bits)
        unsigned long long diag = bufc[lane * 64 + c];

        unsigned rl = __builtin_amdgcn_readlane((int)(unsigned)(rem & 0xffffffffu), c);
        unsigned rh = __builtin_amdgcn_readlane((int)(unsigned)(rem >> 32), c);
        unsigned long long cur = ((unsigned long long)rh << 32) | rl;
        int nrow = M - j0;
        unsigned long long live = ~cur;
        if (nrow < 64) live &= (1ull << nrow) - 1ull;

        unsigned long long am = 0ull;   // accepted-in-this-chunk bits (uniform)
        while (live && cnt < MAXOUT) {
            int jj = __builtin_ctzll(live);
            jj = __builtin_amdgcn_readfirstlane(jj);
            unsigned dl = __builtin_amdgcn_readlane((int)(unsigned)(diag & 0xffffffffu), jj);
            unsigned dh = __builtin_amdgcn_readlane((int)(unsigned)(diag >> 32), jj);
            unsigned long long dw = ((unsigned long long)dh << 32) | dl;
            sel[cnt] = j0 + jj;          // all lanes, same addr, same value
            ++cnt;
            am |= (1ull << jj);
            live &= ~(dw | (1ull << jj));
        }

        // fold accepted rows' mask words into rem: lane l ORs word l of row k.
        if (am) {
#pragma unroll
            for (int k = 0; k < 64; ++k) {
                unsigned long long v = bufc[k * 64 + lane];
                unsigned long long mk = 0ull - ((am >> k) & 1ull);
                rem |= (v & mk);
            }
        }
    }
    // don't let in-flight global_load_lds writes outlive the workgroup
    asm volatile("s_waitcnt vmcnt(0)" ::: "memory");

    __syncthreads();
    const float4* c4 = (const float4*)(cand + (size_t)b * KPRE * 4);
    float4* o4 = (float4*)(out + (size_t)b * MAXOUT * 4);
    for (int r = lane; r < MAXOUT; r += 64) {
        float4 v = make_float4(0.0f, 0.0f, 0.0f, 0.0f);
        if (r < cnt) v = c4[sel[r]];
        o4[r] = v;
    }
}

// ---------------- launch ------------------------------------------------------
extern "C" void kernel_launch(void* const* d_in, const int* in_sizes, int n_in,
                              void* d_out, int out_size, void* d_ws, size_t ws_size,
                              hipStream_t stream) {
    const float* score   = (const float*)d_in[0];
    const float* delta   = (const float*)d_in[1];
    const float* anchors = (const float*)d_in[2];
    float* out = (float*)d_out;

    uint8_t* w8 = (uint8_t*)d_ws;
    // layout (bytes):
    //   hist/bcnt : [0, 131072)            8 x 4096 u32 (hist, then reused as bcnt)
    //   start     : [131072, 262144)       8 x 4096 u32 bucket start offsets
    //   meta      : [262144, 262272)       cut[8] | P[8] | M[8]
    //   keys      : [262272, 532608)       8 x 4224 u64
    //   cand      : [532608, 1044608)      8 x 4000 x 4 f32
    //   mask      : [1044608, 17428608)    8 x 4000 x 64 u64
    unsigned* hist = (unsigned*)(w8 + 0);
    unsigned* start = (unsigned*)(w8 + 131072);
    unsigned* meta = (unsigned*)(w8 + 262144);
    unsigned long long* keys = (unsigned long long*)(w8 + 262272);
    float* cand = (float*)(w8 + 532608);
    unsigned long long* mask = (unsigned long long*)(w8 + 1044608);

    hipMemsetAsync(hist, 0, 8 * 4096 * sizeof(unsigned), stream);
    k_hist<<<dim3(16, NB), 256, 0, stream>>>(score, hist);
    k_cut<<<NB, 1024, 0, stream>>>(hist, start, meta);
    k_collect<<<dim3(32, NB), 256, 0, stream>>>(score, meta, start, hist /*bcnt*/, keys);
    k_rank_decode<<<dim3((KEYCAP + 255) / 256, NB), 256, 0, stream>>>(keys, start, meta,
                                                                      delta, anchors, cand);
    k_mask<<<dim3((KPRE + 63) / 64, NB), 256, 0, stream>>>(cand, mask);
    k_nms<<<NB, 64, 0, stream>>>(mask, cand, meta, out);
}

// Round 4
// 335.091 us; speedup vs baseline: 2.3661x; 1.2007x over previous
//
#include <hip/hip_runtime.h>
#include <stdint.h>

#define NB 8
#define NH 96
#define NW_ 96
#define NA 9
#define NANCH (NH * NW_ * NA)   // 82944
#define KPRE 4000
#define MAXOUT 2000
#define KEYCAP 4224             // >= KPRE + max expected cut-bucket size
#define WPR 64                  // mask row stride in u64 words (63 used + 1 pad)
#define NWORDS 63               // ceil(4000/64)

typedef unsigned long long u64;

// ---------------- Kernel 1: per-batch histogram of score bits ----------------
__global__ void k_hist(const float* __restrict__ score, unsigned* __restrict__ hist) {
    const int b = blockIdx.y;
    __shared__ unsigned h[4096];
    for (int i = threadIdx.x; i < 4096; i += blockDim.x) h[i] = 0u;
    __syncthreads();
    const float* s = score + (size_t)b * NANCH;
    int start = blockIdx.x * blockDim.x + threadIdx.x;
    int stride = gridDim.x * blockDim.x;
    for (int i = start; i < NANCH; i += stride) {
        float v = s[i];
        if (v > 0.5f) {
            unsigned bits = __float_as_uint(v);
            atomicAdd(&h[(bits >> 11) & 4095u], 1u);
        }
    }
    __syncthreads();
    for (int k = threadIdx.x; k < 4096; k += blockDim.x) {
        unsigned c = h[k];
        if (c) atomicAdd(&hist[b * 4096 + k], c);
    }
}

// ------- Kernel 2: one wave/batch suffix-scan -> starts, cut, P, M ------------
__global__ __launch_bounds__(64) void k_cut(unsigned* __restrict__ hist,
                                            unsigned* __restrict__ start,
                                            unsigned* __restrict__ meta) {
    const int b = blockIdx.x;
    const int lane = threadIdx.x;
    const int base = b * 4096 + lane * 64;
    unsigned v[64];
#pragma unroll
    for (int k = 0; k < 64; ++k) { v[k] = hist[base + k]; }
#pragma unroll
    for (int k = 0; k < 64; ++k) { hist[base + k] = 0u; }   // becomes bcnt
    // suffix-sum within lane segment: v[k] = sum_{j>=k} of segment
#pragma unroll
    for (int k = 62; k >= 0; --k) v[k] += v[k + 1];
    unsigned tot = v[0];
    // inclusive suffix-scan of lane totals across the wave
    unsigned incl = tot;
#pragma unroll
    for (int d = 1; d < 64; d <<= 1) {
        unsigned t = __shfl_down(incl, d);
        if (lane + d < 64) incl += t;
    }
    unsigned sfx_above = incl - tot;          // sum over lanes > lane
    unsigned total = __shfl(incl, 0);
    // start[k] = sfx[k+1]
#pragma unroll
    for (int k = 0; k < 63; ++k) start[base + k] = v[k + 1] + sfx_above;
    start[base + 63] = sfx_above;
    if (lane == 0) {
        unsigned P = total < KEYCAP ? total : KEYCAP;
        meta[b] = 0u;
        meta[8 + b] = P;
        meta[16 + b] = P < KPRE ? P : KPRE;
    }
    // crossing: sfx[k] >= KPRE && sfx[k+1] < KPRE (unique)
#pragma unroll
    for (int k = 0; k < 64; ++k) {
        unsigned sfxk = v[k] + sfx_above;
        unsigned nxt = (k < 63) ? (v[k + 1] + sfx_above) : sfx_above;
        if (sfxk >= (unsigned)KPRE && nxt < (unsigned)KPRE) {
            unsigned P = sfxk < KEYCAP ? sfxk : KEYCAP;
            meta[b] = (unsigned)(lane * 64 + k);
            meta[8 + b] = P;
            meta[16 + b] = (unsigned)KPRE;
        }
    }
}

// ---------------- Kernel 3: bucketed scatter of candidate keys ---------------
__global__ void k_collect(const float* __restrict__ score, const unsigned* __restrict__ meta,
                          const unsigned* __restrict__ start, unsigned* __restrict__ bcnt,
                          u64* __restrict__ keys) {
    const int b = blockIdx.y;
    const unsigned cut = meta[b];
    const float* sc = score + (size_t)b * NANCH;
    int i0 = blockIdx.x * blockDim.x + threadIdx.x;
    int stride = gridDim.x * blockDim.x;
    for (int i = i0; i < NANCH; i += stride) {
        float v = sc[i];
        if (v > 0.5f) {
            unsigned bits = __float_as_uint(v);
            unsigned bucket = (bits >> 11) & 4095u;
            if (bucket >= cut) {
                unsigned pos = start[b * 4096 + bucket] + atomicAdd(&bcnt[b * 4096 + bucket], 1u);
                if (pos < (unsigned)KEYCAP)
                    keys[(size_t)b * KEYCAP + pos] =
                        ((u64)bits << 32) | (unsigned)(~(unsigned)i);
            }
        }
    }
}

// -------- Kernel 4: rank within bucket (exact sort position) + decode --------
__global__ void k_rank_decode(const u64* __restrict__ keys,
                              const unsigned* __restrict__ start,
                              const unsigned* __restrict__ meta,
                              const float* __restrict__ delta,
                              const float* __restrict__ anchors,
                              float* __restrict__ cand) {
#pragma clang fp contract(off)
    const int b = blockIdx.y;
    const int s = blockIdx.x * blockDim.x + threadIdx.x;
    const int P = (int)meta[8 + b];
    const int M = (int)meta[16 + b];
    if (s >= M && s < KPRE) {
        float4* c4 = (float4*)(cand + (size_t)b * KPRE * 4);
        c4[s] = make_float4(0.f, 0.f, 0.f, 0.f);
    }
    if (s >= P) return;
    const u64* kb = keys + (size_t)b * KEYCAP;
    u64 key = kb[s];
    unsigned bucket = (unsigned)(key >> 43) & 4095u;
    int base = (int)start[b * 4096 + bucket];
    int end = (bucket > 0) ? (int)start[b * 4096 + bucket - 1] : P;
    if (end > P) end = P;
    int rank = 0;
    for (int t = base; t < end; ++t) rank += (kb[t] > key) ? 1 : 0;
    int pos = base + rank;
    if (pos >= KPRE) return;
    int n = (int)(~(unsigned)(key & 0xFFFFFFFFull));
    float4 t4 = *(const float4*)(delta + ((size_t)b * NANCH + n) * 4);
    float4 a4 = *(const float4*)(anchors + (size_t)n * 4);
    float xa = (a4.x + a4.y) * 0.5f;
    float ya = (a4.z + a4.w) * 0.5f;
    float wa = a4.y - a4.x;
    float ha = a4.w - a4.z;
    float x = t4.x * wa + xa;
    float y = t4.y * ha + ya;
    float w = expf(t4.z) * wa;
    float h = expf(t4.w) * ha;
    float xmn = fminf(fmaxf(x - w * 0.5f, 0.f), 1.f);
    float xmx = fminf(fmaxf(x + w * 0.5f, 0.f), 1.f);
    float ymn = fminf(fmaxf(y - h * 0.5f, 0.f), 1.f);
    float ymx = fminf(fmaxf(y + h * 0.5f, 0.f), 1.f);
    float* o = cand + ((size_t)b * KPRE + pos) * 4;
    o[0] = xmn; o[1] = xmx; o[2] = ymn; o[3] = ymx;
}

// ---------------- Kernel 5: upper-triangle suppression bit matrix ------------
__global__ void k_mask(const float* __restrict__ cand, u64* __restrict__ mask) {
#pragma clang fp contract(off)
    const int b = blockIdx.y;
    const int c = blockIdx.x;       // row chunk of 64
    __shared__ float4 sb4[KPRE];    // 64 KB
    __shared__ float sar[KPRE];     // 16 KB areas
    {
        const float4* c4 = (const float4*)(cand + (size_t)b * KPRE * 4);
        for (int k = threadIdx.x; k < KPRE; k += blockDim.x) {
            float4 v = c4[k];
            sb4[k] = v;
            sar[k] = (v.y - v.x) * (v.w - v.z);
        }
    }
    __syncthreads();
    for (int task = threadIdx.x; task < 64 * NWORDS; task += blockDim.x) {
        const int ri = task & 63;   // lane -> row, word uniform per wave
        const int w = task >> 6;
        const int i = (c << 6) + ri;
        if (i >= KPRE) continue;
        u64 bits = 0ull;
        if (w >= c) {
            float4 bi = sb4[i];
            float ai = sar[i];
            const int j0 = w << 6;
            const int jlim = (j0 + 64 <= KPRE) ? 64 : (KPRE - j0);
            int jj = (w == c) ? ri + 1 : 0;
            for (; jj < jlim; ++jj) {
                float4 bj = sb4[j0 + jj];
                float iw = fminf(bi.y, bj.y) - fmaxf(bi.x, bj.x);
                iw = fmaxf(iw, 0.0f);
                float ih = fminf(bi.w, bj.w) - fmaxf(bi.z, bj.z);
                ih = fmaxf(ih, 0.0f);
                float inter = iw * ih;
                float aj = sar[j0 + jj];
                // safe pre-filter: iou>0.7 => inter > 0.7*union*(1-eps) >= 0.7*max(ai,aj)*(1-eps)
                if (inter > 0.69f * fmaxf(ai, aj)) {
                    float uni = ai + aj - inter;
                    float iou = inter / fmaxf(uni, 1e-8f);
                    if (iou > 0.7f) bits |= (1ull << jj);
                }
            }
        }
        mask[((size_t)b * KPRE + i) * WPR + w] = bits;
    }
}

// ---- Kernel 6: greedy NMS, scalar ctz scan + distance-2 LDS prefetch --------
__device__ __forceinline__ void gl_lds16(const void* g, void* l) {
    __builtin_amdgcn_global_load_lds(
        (const __attribute__((address_space(1))) void*)g,
        (__attribute__((address_space(3))) void*)l, 16, 0, 0);
}
__device__ __forceinline__ u64 readlane64(u64 v, int l) {
    unsigned lo = (unsigned)__builtin_amdgcn_readlane((int)(unsigned)v, l);
    unsigned hi = (unsigned)__builtin_amdgcn_readlane((int)(unsigned)(v >> 32), l);
    return ((u64)hi << 32) | lo;
}
#define WAITVM0  asm volatile("s_waitcnt vmcnt(0)" ::: "memory")
#define WAITVM16 asm volatile("s_waitcnt vmcnt(16)" ::: "memory")
#define WAITVM32 asm volatile("s_waitcnt vmcnt(32)" ::: "memory")
#define WAITLGKM0 asm volatile("s_waitcnt lgkmcnt(0)" ::: "memory")

__global__ __launch_bounds__(64) void k_nms(const u64* __restrict__ mask,
                                            const float* __restrict__ cand,
                                            const unsigned* __restrict__ meta,
                                            float* __restrict__ out) {
    const int b = blockIdx.x;
    const int lane = threadIdx.x;
    const int M = (int)meta[16 + b];
    const u64* mrow = mask + (size_t)b * KPRE * WPR;
    __shared__ u64 buf[3 * 64 * 64];   // 96 KB triple buffer
    __shared__ int sel[MAXOUT];        // 8 KB
    __shared__ u64 amlist_s[64];       // per-chunk accept words
    amlist_s[lane] = 0ull;             // each lane inits its own slot

    u64 rem = 0ull;                    // lane l holds suppression word l
    int cnt = 0;
    const int nchunks = (M + 63) >> 6;

    auto prefetch = [&](int cc) {
        if (cc >= nchunks) return;
        const int j0 = cc << 6;
        const int nrows = (KPRE - j0) < 64 ? (KPRE - j0) : 64;   // even
        const int ninstr = nrows >> 1;                            // 1KB each
        const char* gsrc = (const char*)(mrow + (size_t)j0 * WPR) + lane * 16;
        char* ldst = (char*)buf + (size_t)(cc % 3) * 32768;
#pragma unroll 4
        for (int k = 0; k < ninstr; ++k)
            gl_lds16(gsrc + k * 1024, ldst + k * 1024);
    };

    if (nchunks > 0) {
        prefetch(0);
        prefetch(1);
        if (nchunks > 1) { WAITVM32; } else { WAITVM0; }
        u64 diag = buf[(size_t)(lane << 6)];   // chunk 0, word 0, row lane

        for (int c = 0; c < nchunks && cnt < MAXOUT; ++c) {
            WAITLGKM0;                 // drain reads of buf[(c+2)%3]'s old data
            prefetch(c + 2);
            const u64* bufc = buf + (size_t)(c % 3) * 4096;
            const int j0 = c << 6;

            u64 cur = readlane64(rem, c);
            int nrow = M - j0;
            u64 live = ~cur;
            if (nrow < 64) live &= (1ull << nrow) - 1ull;

            u64 am = 0ull;
            while (live && cnt < MAXOUT) {
                int jj = __builtin_amdgcn_readfirstlane(__builtin_ctzll(live));
                u64 dw = readlane64(diag, jj);
                ++cnt;
                am |= (1ull << jj);
                live &= ~(dw | (1ull << jj));
            }
            if (lane == 0) amlist_s[c] = am;

            // fold accepted rows into rem (4 independent accumulators)
            if (am && cnt < MAXOUT) {
                u64 a0 = 0, a1 = 0, a2 = 0, a3 = 0;
#pragma unroll
                for (int k = 0; k < 64; k += 4) {
                    u64 m0 = 0ull - ((am >> (k + 0)) & 1ull);
                    u64 m1 = 0ull - ((am >> (k + 1)) & 1ull);
                    u64 m2 = 0ull - ((am >> (k + 2)) & 1ull);
                    u64 m3 = 0ull - ((am >> (k + 3)) & 1ull);
                    a0 |= bufc[((k + 0) << 6) + lane] & m0;
                    a1 |= bufc[((k + 1) << 6) + lane] & m1;
                    a2 |= bufc[((k + 2) << 6) + lane] & m2;
                    a3 |= bufc[((k + 3) << 6) + lane] & m3;
                }
                rem |= (a0 | a1) | (a2 | a3);
            }

            // wait for chunk c+1's data, then load its diag word
            int nxt = c + 2;
            if (nxt < nchunks) {
                if (nxt <= 61) { WAITVM32; } else { WAITVM16; }
            } else {
                WAITVM0;
            }
            if (c + 1 < nchunks)
                diag = buf[(size_t)((c + 1) % 3) * 4096 + (lane << 6) + (c + 1)];
        }
        WAITVM0;   // drain any in-flight global_load_lds before LDS reuse/exit
    }

    __syncthreads();
    // expand amlist -> sel (wave-parallel, order-preserving)
    u64 myam = amlist_s[lane];
    int inc = __builtin_popcountll(myam);
    int scan = inc;
#pragma unroll
    for (int d = 1; d < 64; d <<= 1) {
        int t = __shfl_up(scan, d);
        if (lane >= d) scan += t;
    }
    int pos = scan - inc;
    while (myam) {
        int r = __builtin_ctzll(myam);
        myam &= myam - 1;
        sel[pos++] = (lane << 6) + r;
    }
    __syncthreads();

    const float4* c4 = (const float4*)(cand + (size_t)b * KPRE * 4);
    float4* o4 = (float4*)(out + (size_t)b * MAXOUT * 4);
    for (int r = lane; r < MAXOUT; r += 64) {
        float4 v = make_float4(0.0f, 0.0f, 0.0f, 0.0f);
        if (r < cnt) v = c4[sel[r]];
        o4[r] = v;
    }
}

// ---------------- launch ------------------------------------------------------
extern "C" void kernel_launch(void* const* d_in, const int* in_sizes, int n_in,
                              void* d_out, int out_size, void* d_ws, size_t ws_size,
                              hipStream_t stream) {
    const float* score   = (const float*)d_in[0];
    const float* delta   = (const float*)d_in[1];
    const float* anchors = (const float*)d_in[2];
    float* out = (float*)d_out;

    uint8_t* w8 = (uint8_t*)d_ws;
    unsigned* hist = (unsigned*)(w8 + 0);                 // 8 x 4096 u32 (then bcnt)
    unsigned* start = (unsigned*)(w8 + 131072);           // 8 x 4096 u32
    unsigned* meta = (unsigned*)(w8 + 262144);            // cut[8] | P[8] | M[8]
    u64* keys = (u64*)(w8 + 262272);                      // 8 x 4224 u64
    float* cand = (float*)(w8 + 532608);                  // 8 x 4000 x 4 f32
    u64* mask = (u64*)(w8 + 1044608);                     // 8 x 4000 x 64 u64

    hipMemsetAsync(hist, 0, 8 * 4096 * sizeof(unsigned), stream);
    k_hist<<<dim3(16, NB), 256, 0, stream>>>(score, hist);
    k_cut<<<NB, 64, 0, stream>>>(hist, start, meta);
    k_collect<<<dim3(32, NB), 256, 0, stream>>>(score, meta, start, hist /*bcnt*/, keys);
    k_rank_decode<<<dim3((KEYCAP + 255) / 256, NB), 256, 0, stream>>>(keys, start, meta,
                                                                      delta, anchors, cand);
    k_mask<<<dim3((KPRE + 63) / 64, NB), 256, 0, stream>>>(cand, mask);
    k_nms<<<NB, 64, 0, stream>>>(mask, cand, meta, out);
}